// Round 5
// baseline (1316.275 us; speedup 1.0000x reference)
//
#include <hip/hip_runtime.h>
#include <math.h>

#define NNODES 50000
#define NEDGES 800000
#define EMB 256
#define HID 512

// ================= split-bf16 MFMA GEMM =================
// C = act(A @ B + bias), A fp32 [M,K] (K%64==0, lda%4==0), B given pre-transposed
// + split as BTh/BTl [N,K] bf16 (N%128==0). 128x128 block tile, BK=64, 4 waves,
// 64x64 per wave, mfma_f32_16x16x32_bf16, 3 products (hi*hi + lo*hi + hi*lo).
// v5: A-prefetch issued AFTER the barrier (so it overlaps compute instead of being
//     drained by the barrier's vmcnt(0)), and product-major MFMA ordering (same-acc
//     MFMAs 16 instructions apart -> no in-order dependency stalls).

typedef __bf16 bf16x8 __attribute__((ext_vector_type(8)));
typedef float f32x4 __attribute__((ext_vector_type(4)));
typedef unsigned short us4v __attribute__((ext_vector_type(4)));
typedef unsigned short us8v __attribute__((ext_vector_type(8)));

__device__ __forceinline__ unsigned short f2bf(float x) {
    unsigned int u = __float_as_uint(x);
    u += 0x7FFF + ((u >> 16) & 1);          // RTNE
    return (unsigned short)(u >> 16);
}

__device__ __forceinline__ f32x4 mfma_bf16(us8v a, us8v b, f32x4 c) {
    return __builtin_amdgcn_mfma_f32_16x16x32_bf16(
        __builtin_bit_cast(bf16x8, a), __builtin_bit_cast(bf16x8, b), c, 0, 0, 0);
}

// weight prep: W [K,N] fp32 -> WTh/WTl [N,K] bf16 (hi/lo split)
__global__ void wsplit(const float* __restrict__ W, int K, int N,
                       unsigned short* __restrict__ th, unsigned short* __restrict__ tl)
{
    int idx = blockIdx.x * 256 + threadIdx.x;
    if (idx >= K * N) return;
    int n = idx / K, k = idx - n * K;
    float x = W[(size_t)k * N + n];
    unsigned short h = f2bf(x);
    float hf = __uint_as_float((unsigned int)h << 16);
    th[idx] = h;
    tl[idx] = f2bf(x - hf);
}

__global__ __launch_bounds__(256) void gemm_mfma(
    const float* __restrict__ A, int lda,
    const unsigned short* __restrict__ BTh, const unsigned short* __restrict__ BTl,
    float* __restrict__ C, int ldc, float* __restrict__ C2,
    const float* __restrict__ bias, int M, int N, int K, int act)
{
    // A tile, split hi/lo bf16, double-buffered.
    // Element (m,kk) at m*64 + (((kk>>3) ^ (m&7))<<3) + (kk&7)   (16B-block XOR swizzle)
    __shared__ unsigned short AsH[2][128 * 64];
    __shared__ unsigned short AsL[2][128 * 64];
    const int bm = blockIdx.y * 128;
    const int bn = blockIdx.x * 128;
    const int tid = threadIdx.x;
    const int lane = tid & 63;
    const int wid = tid >> 6;                // 4 waves
    const int wm = wid >> 1, wn = wid & 1;   // 2x2 wave grid, 64x64 each
    const int l15 = lane & 15, l4 = lane >> 4;

    // staging geometry (fixed per thread across K-tiles)
    int smidx[8], sj4[8];
    const float* sptr[8];
#pragma unroll
    for (int u = 0; u < 8; ++u) {
        int fid = tid + u * 256;             // 0..2047 float4 units
        int m = fid >> 4;                    // 0..127
        int j4 = fid & 15;                   // float4 along K
        smidx[u] = m;
        sj4[u] = j4;
        int gr = bm + m;
        sptr[u] = (gr < M) ? (A + (size_t)gr * lda + j4 * 4) : nullptr;
    }

    // B fragment base pointers (per wave/lane, fixed across K)
    const unsigned short* bhp[4];
    const unsigned short* blp[4];
#pragma unroll
    for (int fj = 0; fj < 4; ++fj) {
        size_t coff = (size_t)(bn + wn * 64 + fj * 16 + l15) * (size_t)K;
        bhp[fj] = BTh + coff;
        blp[fj] = BTl + coff;
    }

    f32x4 acc[4][4] = {};
    float4 pref[8];

    const int nk = K >> 6;                   // K/64 tiles

    // prologue: load tile 0 into regs
#pragma unroll
    for (int u = 0; u < 8; ++u)
        pref[u] = sptr[u] ? *(const float4*)(sptr[u]) : make_float4(0.f, 0.f, 0.f, 0.f);

    for (int t = 0; t < nk; ++t) {
        const int cur = t & 1;
        // ---- convert prefetched A regs -> hi/lo bf16 in LDS[cur] ----
#pragma unroll
        for (int u = 0; u < 8; ++u) {
            float e[4] = {pref[u].x, pref[u].y, pref[u].z, pref[u].w};
            us4v h, l;
#pragma unroll
            for (int q = 0; q < 4; ++q) {
                unsigned short hh = f2bf(e[q]);
                h[q] = hh;
                l[q] = f2bf(e[q] - __uint_as_float((unsigned int)hh << 16));
            }
            int m = smidx[u], j4 = sj4[u];
            int phys = m * 64 + ((((j4 >> 1)) ^ (m & 7)) << 3) + (j4 & 1) * 4;
            *(us4v*)&AsH[cur][phys] = h;
            *(us4v*)&AsL[cur][phys] = l;
        }
        __syncthreads();

        // ---- issue next-tile global loads AFTER the barrier so they stay in flight
        //      during compute (a pre-barrier issue is drained by the barrier's
        //      vmcnt(0) and hides under nothing) ----
        if (t + 1 < nk) {
            const int koff = (t + 1) * 64;
#pragma unroll
            for (int u = 0; u < 8; ++u)
                pref[u] = sptr[u] ? *(const float4*)(sptr[u] + koff)
                                  : make_float4(0.f, 0.f, 0.f, 0.f);
        }

        // ---- compute on LDS[cur]: two K=32 MFMA steps ----
        const int k0 = t * 64;
#pragma unroll
        for (int ks = 0; ks < 2; ++ks) {
            us8v ah[4], al[4], bh[4], bl[4];
            const int kb = ks * 4 + l4;
#pragma unroll
            for (int fi = 0; fi < 4; ++fi) {
                int row = wm * 64 + fi * 16 + l15;
                int phys = row * 64 + ((kb ^ (row & 7)) << 3);
                ah[fi] = *(const us8v*)&AsH[cur][phys];
                al[fi] = *(const us8v*)&AsL[cur][phys];
            }
            const size_t kg = (size_t)(k0 + ks * 32 + l4 * 8);
#pragma unroll
            for (int fj = 0; fj < 4; ++fj) {
                bh[fj] = *(const us8v*)(bhp[fj] + kg);
                bl[fj] = *(const us8v*)(blp[fj] + kg);
            }
            // product-major order: same accumulator revisited only every 16 MFMAs,
            // so the in-order wave never stalls on MFMA result latency
#pragma unroll
            for (int fj = 0; fj < 4; ++fj)
#pragma unroll
                for (int fi = 0; fi < 4; ++fi)
                    acc[fi][fj] = mfma_bf16(ah[fi], bh[fj], acc[fi][fj]);
#pragma unroll
            for (int fj = 0; fj < 4; ++fj)
#pragma unroll
                for (int fi = 0; fi < 4; ++fi)
                    acc[fi][fj] = mfma_bf16(al[fi], bh[fj], acc[fi][fj]);
#pragma unroll
            for (int fj = 0; fj < 4; ++fj)
#pragma unroll
                for (int fi = 0; fi < 4; ++fi)
                    acc[fi][fj] = mfma_bf16(ah[fi], bl[fj], acc[fi][fj]);
        }
        // single barrier per tile: buffer cur is rewritten only after the NEXT
        // barrier, which all waves reach only after finishing this compute
    }

    // ---- epilogue: C/D layout col=lane&15, row=(lane>>4)*4+r ----
    float bs[4];
#pragma unroll
    for (int fj = 0; fj < 4; ++fj)
        bs[fj] = bias ? bias[bn + wn * 64 + fj * 16 + l15] : 0.f;

#pragma unroll
    for (int fi = 0; fi < 4; ++fi) {
#pragma unroll
        for (int r = 0; r < 4; ++r) {
            int row = bm + wm * 64 + fi * 16 + l4 * 4 + r;
            if (row >= M) continue;
#pragma unroll
            for (int fj = 0; fj < 4; ++fj) {
                int col = bn + wn * 64 + fj * 16 + l15;
                float v = acc[fi][fj][r] + bs[fj];
                if (act) v = v > 0.f ? v : 0.01f * v;
                C[(size_t)row * ldc + col] = v;
                if (C2) C2[(size_t)row * ldc + col] = v;
            }
        }
    }
}

// ================= fp32 fallback GEMM (used for K=13 slices) =================
#define BM 128
#define BN 128
#define BK 16

__global__ __launch_bounds__(256) void gemm_kernel(
    const float* __restrict__ A, int lda,
    const float* __restrict__ B, int ldb,
    float* __restrict__ C, int ldc,
    float* __restrict__ C2,
    const float* __restrict__ bias,
    int M, int N, int K, int act)
{
    __shared__ float As[BK][BM];   // element (k,m) stored at As[k][m ^ ((k&7)<<2)]
    __shared__ float Bs[BK][BN];   // linear
    const int bm = blockIdx.y * BM;
    const int bn = blockIdx.x * BN;
    const int tid = threadIdx.x;
    const int tx = tid & 15;
    const int ty = tid >> 4;

    const bool avec = ((((uintptr_t)A) & 15) == 0) && ((lda & 3) == 0);

    float acc[8][8] = {};

    for (int k0 = 0; k0 < K; k0 += BK) {
        if (avec) {
#pragma unroll
            for (int it = 0; it < 2; ++it) {
                int aid = tid + it * 256;
                int m = aid >> 2;
                int kq = aid & 3;
                int gr = bm + m;
                int gk = k0 + kq * 4;
                float4 v = {0.f, 0.f, 0.f, 0.f};
                if (gr < M) {
                    if (gk + 3 < K) {
                        v = *(const float4*)(A + (size_t)gr * lda + gk);
                    } else {
                        float t0 = (gk + 0 < K) ? A[(size_t)gr * lda + gk + 0] : 0.f;
                        float t1 = (gk + 1 < K) ? A[(size_t)gr * lda + gk + 1] : 0.f;
                        float t2 = (gk + 2 < K) ? A[(size_t)gr * lda + gk + 2] : 0.f;
                        float t3 = (gk + 3 < K) ? A[(size_t)gr * lda + gk + 3] : 0.f;
                        v = make_float4(t0, t1, t2, t3);
                    }
                }
                int k = kq * 4;
                As[k + 0][m ^ (((k + 0) & 7) << 2)] = v.x;
                As[k + 1][m ^ (((k + 1) & 7) << 2)] = v.y;
                As[k + 2][m ^ (((k + 2) & 7) << 2)] = v.z;
                As[k + 3][m ^ (((k + 3) & 7) << 2)] = v.w;
            }
        } else {
            for (int l = tid; l < BM * BK; l += 256) {
                int m = l >> 4;
                int k = l & 15;
                int gr = bm + m, gc = k0 + k;
                float v = (gr < M && gc < K) ? A[(size_t)gr * lda + gc] : 0.f;
                As[k][m ^ ((k & 7) << 2)] = v;
            }
        }
#pragma unroll
        for (int it = 0; it < 2; ++it) {
            int fid = tid + it * 256;
            int k = fid >> 5;
            int n4 = fid & 31;
            int gk = k0 + k;
            int gn = bn + n4 * 4;
            float4 v = {0.f, 0.f, 0.f, 0.f};
            if (gk < K) {
                if (gn + 3 < N) {
                    v = *(const float4*)(B + (size_t)gk * ldb + gn);
                } else {
                    float t0 = (gn + 0 < N) ? B[(size_t)gk * ldb + gn + 0] : 0.f;
                    float t1 = (gn + 1 < N) ? B[(size_t)gk * ldb + gn + 1] : 0.f;
                    float t2 = (gn + 2 < N) ? B[(size_t)gk * ldb + gn + 2] : 0.f;
                    float t3 = (gn + 3 < N) ? B[(size_t)gk * ldb + gn + 3] : 0.f;
                    v = make_float4(t0, t1, t2, t3);
                }
            }
            *(float4*)&Bs[k][n4 * 4] = v;
        }
        __syncthreads();

#pragma unroll
        for (int k = 0; k < BK; ++k) {
            const int sw = (k & 7) << 2;
            float4 a0 = *(const float4*)&As[k][(ty * 4) ^ sw];
            float4 a1 = *(const float4*)&As[k][(ty * 4 + 64) ^ sw];
            float4 b0 = *(const float4*)&Bs[k][tx * 4];
            float4 b1 = *(const float4*)&Bs[k][tx * 4 + 64];
            float av[8] = {a0.x, a0.y, a0.z, a0.w, a1.x, a1.y, a1.z, a1.w};
            float bv[8] = {b0.x, b0.y, b0.z, b0.w, b1.x, b1.y, b1.z, b1.w};
#pragma unroll
            for (int i = 0; i < 8; ++i)
#pragma unroll
                for (int j = 0; j < 8; ++j)
                    acc[i][j] += av[i] * bv[j];
        }
        __syncthreads();
    }

#pragma unroll
    for (int i = 0; i < 8; ++i) {
        int r = bm + ((i >> 2) * 64) + ty * 4 + (i & 3);
        if (r >= M) continue;
#pragma unroll
        for (int jh = 0; jh < 2; ++jh) {
            int c0 = bn + jh * 64 + tx * 4;
            if (c0 + 3 < N) {
                float v0 = acc[i][jh * 4 + 0];
                float v1 = acc[i][jh * 4 + 1];
                float v2 = acc[i][jh * 4 + 2];
                float v3 = acc[i][jh * 4 + 3];
                if (bias) {
                    v0 += bias[c0 + 0]; v1 += bias[c0 + 1];
                    v2 += bias[c0 + 2]; v3 += bias[c0 + 3];
                }
                if (act) {
                    v0 = v0 > 0.f ? v0 : 0.01f * v0;
                    v1 = v1 > 0.f ? v1 : 0.01f * v1;
                    v2 = v2 > 0.f ? v2 : 0.01f * v2;
                    v3 = v3 > 0.f ? v3 : 0.01f * v3;
                }
                float4 pack = make_float4(v0, v1, v2, v3);
                *(float4*)(C + (size_t)r * ldc + c0) = pack;
                if (C2) *(float4*)(C2 + (size_t)r * ldc + c0) = pack;
            } else {
#pragma unroll
                for (int e = 0; e < 4; ++e) {
                    int c = c0 + e;
                    if (c >= N) continue;
                    float v = acc[i][jh * 4 + e];
                    if (bias) v += bias[c];
                    if (act) v = v > 0.f ? v : 0.01f * v;
                    C[(size_t)r * ldc + c] = v;
                    if (C2) C2[(size_t)r * ldc + c] = v;
                }
            }
        }
    }
}

// ---------------- CSR build ----------------
__global__ void count_deg(const int* __restrict__ dst, int* __restrict__ deg, int nE)
{
    int e = blockIdx.x * 256 + threadIdx.x;
    if (e < nE) atomicAdd(&deg[dst[e]], 1);
}

__global__ void dinv_kernel(const int* __restrict__ deg, float* __restrict__ dinv, int n)
{
    int i = blockIdx.x * 256 + threadIdx.x;
    if (i < n) dinv[i] = rsqrtf((float)deg[i] + 1.0f);   // +1 for self loop
}

__global__ __launch_bounds__(256) void scan1(const int* __restrict__ deg,
                                             int* __restrict__ excl,
                                             int* __restrict__ blocksum, int n)
{
    __shared__ int tsum[256];
    int base = blockIdx.x * 1024;
    int t = threadIdx.x;
    int v[4], s = 0;
#pragma unroll
    for (int j = 0; j < 4; ++j) {
        int idx = base + t * 4 + j;
        v[j] = (idx < n) ? deg[idx] : 0;
        s += v[j];
    }
    tsum[t] = s;
    __syncthreads();
    for (int off = 1; off < 256; off <<= 1) {
        int x = (t >= off) ? tsum[t - off] : 0;
        __syncthreads();
        tsum[t] += x;
        __syncthreads();
    }
    int toff = tsum[t] - s;
    int run = 0;
#pragma unroll
    for (int j = 0; j < 4; ++j) {
        int idx = base + t * 4 + j;
        if (idx < n) excl[idx] = toff + run;
        run += v[j];
    }
    if (t == 255) blocksum[blockIdx.x] = tsum[255];
}

__global__ void scan2(int* __restrict__ blocksum, int nb)
{
    if (threadIdx.x == 0 && blockIdx.x == 0) {
        int run = 0;
        for (int i = 0; i < nb; ++i) {
            int v = blocksum[i];
            blocksum[i] = run;
            run += v;
        }
    }
}

__global__ void scan3(int* __restrict__ rowptr, int* __restrict__ cursor,
                      const int* __restrict__ excl, const int* __restrict__ blocksum, int n)
{
    int idx = blockIdx.x * 256 + threadIdx.x;
    if (idx < n) {
        int v = excl[idx] + blocksum[idx >> 10];
        rowptr[idx] = v;
        cursor[idx] = v;
    }
    if (idx == 0) rowptr[n] = NEDGES;
}

__global__ void fill_csr(const int* __restrict__ src, const int* __restrict__ dst,
                         const float* __restrict__ dinv, int* __restrict__ cursor,
                         int* __restrict__ src_sorted, float* __restrict__ w_sorted, int nE)
{
    int e = blockIdx.x * 256 + threadIdx.x;
    if (e >= nE) return;
    int s = src[e], d = dst[e];
    int pos = atomicAdd(&cursor[d], 1);
    src_sorted[pos] = s;
    w_sorted[pos] = dinv[s] * dinv[d];
}

// ---------------- fused GCN aggregation ----------------
__global__ __launch_bounds__(256) void gather_conv(
    const float* __restrict__ t, const int* __restrict__ rowptr,
    const int* __restrict__ src_sorted, const float* __restrict__ w_sorted,
    const float* __restrict__ dinv, const float* __restrict__ bias,
    float* __restrict__ out, int ldc)
{
    int node = blockIdx.x * 4 + (threadIdx.x >> 6);
    if (node >= NNODES) return;
    int lane = threadIdx.x & 63;
    int p0 = rowptr[node], p1 = rowptr[node + 1];
    const float4* tv = (const float4*)t;
    float4 acc = {0.f, 0.f, 0.f, 0.f};
    for (int p = p0; p < p1; ++p) {
        int s = src_sorted[p];
        float w = w_sorted[p];
        float4 v = tv[(size_t)s * 64 + lane];
        acc.x += v.x * w; acc.y += v.y * w; acc.z += v.z * w; acc.w += v.w * w;
    }
    float di = dinv[node];
    float w2 = di * di;
    float4 self = tv[(size_t)node * 64 + lane];
    float4 b = ((const float4*)bias)[lane];
    acc.x += self.x * w2 + b.x;
    acc.y += self.y * w2 + b.y;
    acc.z += self.z * w2 + b.z;
    acc.w += self.w * w2 + b.w;
    acc.x = acc.x > 0.f ? acc.x : 0.01f * acc.x;
    acc.y = acc.y > 0.f ? acc.y : 0.01f * acc.y;
    acc.z = acc.z > 0.f ? acc.z : 0.01f * acc.z;
    acc.w = acc.w > 0.f ? acc.w : 0.01f * acc.w;
    *((float4*)(out + (size_t)node * ldc) + lane) = acc;
}

// ---------------- final: s_ci = sigmoid(s @ Wl2 + bl2), replicate x3 ----------------
__global__ __launch_bounds__(256) void rowdot_sigmoid(
    const float* __restrict__ s, const float* __restrict__ w, const float* __restrict__ b,
    float* __restrict__ out, int n)
{
    int row = blockIdx.x * 4 + (threadIdx.x >> 6);
    int lane = threadIdx.x & 63;
    if (row >= n) return;
    const float4* sr = (const float4*)(s + (size_t)row * 256);
    const float4* wr = (const float4*)w;
    float4 a = sr[lane], c = wr[lane];
    float p = a.x * c.x + a.y * c.y + a.z * c.z + a.w * c.w;
#pragma unroll
    for (int off = 32; off > 0; off >>= 1) p += __shfl_down(p, off);
    if (lane == 0) {
        float v = 1.0f / (1.0f + expf(-(p + b[0])));
        out[row] = v;
        out[n + row] = v;
        out[2 * n + row] = v;
    }
}

extern "C" void kernel_launch(void* const* d_in, const int* in_sizes, int n_in,
                              void* d_out, int out_size, void* d_ws, size_t ws_size,
                              hipStream_t stream)
{
    const float* discrete_x = (const float*)d_in[0];
    const float* continous_x = (const float*)d_in[1];
    const float* Wd  = (const float*)d_in[2];  const float* bd  = (const float*)d_in[3];
    const float* Wc1 = (const float*)d_in[4];  const float* bc1 = (const float*)d_in[5];
    const float* Wc2 = (const float*)d_in[6];  const float* bc2 = (const float*)d_in[7];
    const float* Wg0 = (const float*)d_in[8];  const float* bg0 = (const float*)d_in[9];
    const float* Wg1 = (const float*)d_in[10]; const float* bg1 = (const float*)d_in[11];
    const float* Wg2 = (const float*)d_in[12]; const float* bg2 = (const float*)d_in[13];
    const float* Wf  = (const float*)d_in[14]; const float* bf  = (const float*)d_in[15];
    const float* Wl1 = (const float*)d_in[16]; const float* bl1 = (const float*)d_in[17];
    const float* Wl2 = (const float*)d_in[18]; const float* bl2 = (const float*)d_in[19];
    const int* edge_index = (const int*)d_in[20];
    const int* src = edge_index;
    const int* dst = edge_index + NEDGES;

    float* out = (float*)d_out;
    float* ws = (float*)d_ws;

    // workspace layout — IDENTICAL footprint to the last passing run (ends at sbuf end)
    float* dinv       = ws;
    int*   deg        = (int*)(ws + 50048);
    int*   rowptr     = (int*)(ws + 2 * 50048);
    int*   cursor     = (int*)(ws + 3 * 50048 + 64);
    int*   excl       = (int*)(ws + 4 * 50048 + 64);
    int*   blocksum   = (int*)(ws + 5 * 50048 + 64);
    int*   src_sorted = (int*)(ws + 5 * 50048 + 128);
    float* w_sorted   = ws + 5 * 50048 + 128 + NEDGES;
    float* xcat       = w_sorted + NEDGES;                     // NNODES*1024
    float* xg         = xcat + (size_t)NNODES * 1024;          // NNODES*256
    float* tbuf       = xg   + (size_t)NNODES * EMB;           // NNODES*256
    float* sbuf       = tbuf + (size_t)NNODES * EMB;           // NNODES*256 (end of ws use)

    float* h_out  = out + 3 * (size_t)NNODES;                  // NNODES * 512 (in d_out)
    float* h_out2 = h_out + (size_t)NNODES * HID;              // NNODES * 512 (in d_out)

    // split-bf16 weights live in DEAD regions (no workspace extension):
    //  - wl1 in out[0:3N): written only by rowdot_sigmoid (last kernel)
    //  - wd/wg0/wg1/wg2 in h_out2: written only by the Wf gemm dual-store
    //  - wf in sbuf head: sbuf first written by the Wl1 gemm (after Wf consumed wf)
    unsigned short* wl1_h = (unsigned short*)out;
    unsigned short* wl1_l = wl1_h + 512 * 256;
    unsigned short* wd_h  = (unsigned short*)h_out2;
    unsigned short* wd_l  = wd_h  + 64 * 256;
    unsigned short* wg0_h = wd_l  + 64 * 256;
    unsigned short* wg0_l = wg0_h + 64 * 256;
    unsigned short* wg1_h = wg0_l + 64 * 256;
    unsigned short* wg1_l = wg1_h + 256 * 256;
    unsigned short* wg2_h = wg1_l + 256 * 256;
    unsigned short* wg2_l = wg2_h + 256 * 256;
    unsigned short* wf_h  = (unsigned short*)sbuf;
    unsigned short* wf_l  = wf_h + 1024 * 512;

    dim3 blk(256);
    auto gemmF = [&](const float* A, int lda, const float* B, int ldb, float* C, int ldc,
                     float* C2, const float* bias, int M, int N, int K, int act) {
        dim3 grid((N + BN - 1) / BN, (M + BM - 1) / BM);
        hipLaunchKernelGGL(gemm_kernel, grid, blk, 0, stream,
                           A, lda, B, ldb, C, ldc, C2, bias, M, N, K, act);
    };
    auto gemmM = [&](const float* A, int lda, const unsigned short* th, const unsigned short* tl,
                     float* C, int ldc, float* C2, const float* bias,
                     int M, int N, int K, int act) {
        dim3 grid(N / 128, (M + 127) / 128);
        hipLaunchKernelGGL(gemm_mfma, grid, blk, 0, stream,
                           A, lda, th, tl, C, ldc, C2, bias, M, N, K, act);
    };
    auto wsp = [&](const float* W, int K, int N, unsigned short* th, unsigned short* tl) {
        hipLaunchKernelGGL(wsplit, dim3((K * N + 255) / 256), blk, 0, stream, W, K, N, th, tl);
    };

    // ---- weight split/transpose prologue (tiny) ----
    wsp(Wd,  64,   256, wd_h,  wd_l);
    wsp(Wg0, 64,   256, wg0_h, wg0_l);
    wsp(Wg1, 256,  256, wg1_h, wg1_l);
    wsp(Wg2, 256,  256, wg2_h, wg2_l);
    wsp(Wf,  1024, 512, wf_h,  wf_l);
    wsp(Wl1, 512,  256, wl1_h, wl1_l);

    // ---- CSR build (once) + dinv ----
    hipMemsetAsync(deg, 0, NNODES * sizeof(int), stream);
    hipLaunchKernelGGL(count_deg, dim3((NEDGES + 255) / 256), blk, 0, stream, dst, deg, NEDGES);
    hipLaunchKernelGGL(dinv_kernel, dim3((NNODES + 255) / 256), blk, 0, stream, deg, dinv, NNODES);
    int nb = (NNODES + 1023) / 1024;
    hipLaunchKernelGGL(scan1, dim3(nb), blk, 0, stream, deg, excl, blocksum, NNODES);
    hipLaunchKernelGGL(scan2, dim3(1), blk, 0, stream, blocksum, nb);
    hipLaunchKernelGGL(scan3, dim3((NNODES + 255) / 256), blk, 0, stream,
                       rowptr, cursor, excl, blocksum, NNODES);
    hipLaunchKernelGGL(fill_csr, dim3((NEDGES + 255) / 256), blk, 0, stream,
                       src, dst, dinv, cursor, src_sorted, w_sorted, NEDGES);

    // ---- embeddings into concat buffer [N,1024] = [x_d | x_c1 | x_c2 | x_g2] ----
    gemmM(discrete_x, 64, wd_h, wd_l, xcat + 0, 1024, nullptr, bd, NNODES, 256, 64, 1);
    gemmF(continous_x,      39, Wc1, EMB, xcat + 256, 1024, nullptr, bc1, NNODES, EMB, 13, 1);
    gemmF(continous_x + 13, 39, Wc2, EMB, xcat + 512, 1024, nullptr, bc2, NNODES, EMB, 13, 1);
    gemmM(discrete_x, 64, wg0_h, wg0_l, xg, EMB, nullptr, bg0, NNODES, 256, 64, 1);

    // ---- GCN conv 1 ----
    gemmM(xg, EMB, wg1_h, wg1_l, tbuf, EMB, nullptr, nullptr, NNODES, 256, 256, 0);
    hipLaunchKernelGGL(gather_conv, dim3((NNODES + 3) / 4), blk, 0, stream,
                       tbuf, rowptr, src_sorted, w_sorted, dinv, bg1, xg, EMB);

    // ---- GCN conv 2 -> concat column 768 ----
    gemmM(xg, EMB, wg2_h, wg2_l, tbuf, EMB, nullptr, nullptr, NNODES, 256, 256, 0);
    hipLaunchKernelGGL(gather_conv, dim3((NNODES + 3) / 4), blk, 0, stream,
                       tbuf, rowptr, src_sorted, w_sorted, dinv, bg2, xcat + 768, 1024);

    // ---- h_ci = lrelu(xcat @ Wf + bf) -> both d_out slots (clobbers wd..wg2, dead) ----
    gemmM(xcat, 1024, wf_h, wf_l, h_out, HID, h_out2, bf, NNODES, 512, 1024, 1);

    // ---- s = lrelu(h @ Wl1 + bl1) -> sbuf (clobbers wf, dead) ----
    gemmM(h_out, HID, wl1_h, wl1_l, sbuf, 256, nullptr, bl1, NNODES, 256, 512, 1);

    // ---- s_ci = sigmoid(s @ Wl2 + bl2) -> out[0:3N] (clobbers wl1, dead) ----
    hipLaunchKernelGGL(rowdot_sigmoid, dim3((NNODES + 3) / 4), blk, 0, stream,
                       sbuf, Wl2, bl2, out, NNODES);
}

// Round 6
// 1301.616 us; speedup vs baseline: 1.0113x; 1.0113x over previous
//
#include <hip/hip_runtime.h>
#include <math.h>

#define NNODES 50000
#define NEDGES 800000
#define EMB 256
#define HID 512

// ================= split-bf16 MFMA GEMM, plane-A version =================
// A given as pre-split hi/lo bf16 planes [M][lda] (lda=K). B pre-transposed+split
// [N][K]. 128x128 tile, BK=64, 4 waves, 64x64/wave, mfma_f32_16x16x32_bf16,
// 3 products. A staged via global_load_lds(16B) with inverse-swizzled SOURCE
// addresses (linear LDS dest), so reads use the XOR swizzle conflict-free.
// B loads issued BEFORE the A-prefetch DMA so their counted vmcnt wait leaves
// the prefetch in flight. One barrier per K-tile (double-buffered LDS).

typedef __bf16 bf16x8 __attribute__((ext_vector_type(8)));
typedef float f32x4 __attribute__((ext_vector_type(4)));
typedef unsigned short us4v __attribute__((ext_vector_type(4)));
typedef unsigned short us8v __attribute__((ext_vector_type(8)));

__device__ __forceinline__ unsigned short f2bf(float x) {
    unsigned int u = __float_as_uint(x);
    u += 0x7FFF + ((u >> 16) & 1);          // RTNE
    return (unsigned short)(u >> 16);
}

__device__ __forceinline__ f32x4 mfma_bf16(us8v a, us8v b, f32x4 c) {
    return __builtin_amdgcn_mfma_f32_16x16x32_bf16(
        __builtin_bit_cast(bf16x8, a), __builtin_bit_cast(bf16x8, b), c, 0, 0, 0);
}

__device__ __forceinline__ void gl16(const unsigned short* g, unsigned short* l) {
    __builtin_amdgcn_global_load_lds(
        (const __attribute__((address_space(1))) unsigned int*)g,
        (__attribute__((address_space(3))) unsigned int*)l, 16, 0, 0);
}

// weight prep: W [K,N] fp32 -> WTh/WTl [N,K] bf16 (hi/lo split)
__global__ void wsplit(const float* __restrict__ W, int K, int N,
                       unsigned short* __restrict__ th, unsigned short* __restrict__ tl)
{
    int idx = blockIdx.x * 256 + threadIdx.x;
    if (idx >= K * N) return;
    int n = idx / K, k = idx - n * K;
    float x = W[(size_t)k * N + n];
    unsigned short h = f2bf(x);
    float hf = __uint_as_float((unsigned int)h << 16);
    th[idx] = h;
    tl[idx] = f2bf(x - hf);
}

// activation prep: X [n] fp32 -> hi/lo planes (row-major copy)
__global__ void xsplit(const float* __restrict__ X, int n,
                       unsigned short* __restrict__ xh, unsigned short* __restrict__ xl)
{
    int i = blockIdx.x * 256 + threadIdx.x;
    if (i >= n) return;
    float x = X[i];
    unsigned short h = f2bf(x);
    xh[i] = h;
    xl[i] = f2bf(x - __uint_as_float((unsigned int)h << 16));
}

__global__ __launch_bounds__(256) void gemm_mfma_p(
    const unsigned short* __restrict__ Ah, const unsigned short* __restrict__ Al, int lda,
    const unsigned short* __restrict__ BTh, const unsigned short* __restrict__ BTl,
    float* __restrict__ C, int ldc, float* __restrict__ C2,
    unsigned short* __restrict__ Ch, unsigned short* __restrict__ Cl, int ldcp,
    const float* __restrict__ bias, int M, int N, int K, int act)
{
    // LDS: element (m,kk) stored at m*64 + (((kk>>3) ^ (m&7))<<3) + (kk&7)
    __shared__ unsigned short AsH[2][128 * 64];
    __shared__ unsigned short AsL[2][128 * 64];
    const int bm = blockIdx.y * 128;
    const int bn = blockIdx.x * 128;
    const int tid = threadIdx.x;
    const int lane = tid & 63;
    const int wid = tid >> 6;                // 4 waves
    const int wm = wid >> 1, wn = wid & 1;   // 2x2 wave grid, 64x64 each
    const int l15 = lane & 15, l4 = lane >> 4;

    // staging: wave stages 4 groups (8 rows each) per plane via global_load_lds.
    // lane l writes LDS byte grp*1024 + l*16 -> row grp*8 + (l>>3), phys block l&7.
    // source block = (l&7) ^ (l>>3) so phys block b at row r holds global block b^(r&7).
    const int rg = lane >> 3;
    const int sb = (lane & 7) ^ rg;
    size_t soff[4];
#pragma unroll
    for (int i = 0; i < 4; ++i) {
        int g = wid * 4 + i;
        soff[i] = (size_t)(bm + g * 8 + rg) * (size_t)lda + (size_t)(sb * 8);
    }

    // B fragment base pointers (per wave/lane, fixed across K)
    const unsigned short* bhp[4];
    const unsigned short* blp[4];
#pragma unroll
    for (int fj = 0; fj < 4; ++fj) {
        size_t coff = (size_t)(bn + wn * 64 + fj * 16 + l15) * (size_t)K;
        bhp[fj] = BTh + coff;
        blp[fj] = BTl + coff;
    }

    f32x4 acc[4][4] = {};
    const int nk = K >> 6;                   // K/64 tiles

    // prologue: DMA tile 0 into buf 0
#pragma unroll
    for (int i = 0; i < 4; ++i) {
        int g = wid * 4 + i;
        gl16(Ah + soff[i], &AsH[0][g * 512]);
        gl16(Al + soff[i], &AsL[0][g * 512]);
    }
    __syncthreads();

    for (int t = 0; t < nk; ++t) {
        const int cur = t & 1;
        const int k0 = t * 64;

        // ---- B loads for BOTH ks-steps, issued first (counted vmcnt won't drain DMA) ----
        us8v bh[2][4], bl[2][4];
#pragma unroll
        for (int ks = 0; ks < 2; ++ks) {
            const size_t kg = (size_t)(k0 + ks * 32 + l4 * 8);
#pragma unroll
            for (int fj = 0; fj < 4; ++fj) {
                bh[ks][fj] = *(const us8v*)(bhp[fj] + kg);
                bl[ks][fj] = *(const us8v*)(blp[fj] + kg);
            }
        }

        // ---- A-prefetch tile t+1 -> buf cur^1 (in flight across the compute) ----
        if (t + 1 < nk) {
            const size_t ko = (size_t)(k0 + 64);
#pragma unroll
            for (int i = 0; i < 4; ++i) {
                int g = wid * 4 + i;
                gl16(Ah + soff[i] + ko, &AsH[cur ^ 1][g * 512]);
                gl16(Al + soff[i] + ko, &AsL[cur ^ 1][g * 512]);
            }
        }

        // ---- compute on buf[cur]: two K=32 MFMA steps, product-major ----
#pragma unroll
        for (int ks = 0; ks < 2; ++ks) {
            us8v ah[4], al[4];
            const int kb = ks * 4 + l4;
#pragma unroll
            for (int fi = 0; fi < 4; ++fi) {
                int row = wm * 64 + fi * 16 + l15;
                int phys = row * 64 + ((kb ^ (row & 7)) << 3);
                ah[fi] = *(const us8v*)&AsH[cur][phys];
                al[fi] = *(const us8v*)&AsL[cur][phys];
            }
#pragma unroll
            for (int fj = 0; fj < 4; ++fj)
#pragma unroll
                for (int fi = 0; fi < 4; ++fi)
                    acc[fi][fj] = mfma_bf16(ah[fi], bh[ks][fj], acc[fi][fj]);
#pragma unroll
            for (int fj = 0; fj < 4; ++fj)
#pragma unroll
                for (int fi = 0; fi < 4; ++fi)
                    acc[fi][fj] = mfma_bf16(al[fi], bh[ks][fj], acc[fi][fj]);
#pragma unroll
            for (int fj = 0; fj < 4; ++fj)
#pragma unroll
                for (int fi = 0; fi < 4; ++fi)
                    acc[fi][fj] = mfma_bf16(ah[fi], bl[ks][fj], acc[fi][fj]);
        }
        // one barrier per tile: drains the DMA (tile t+1 ready) and guarantees all
        // waves finished reading buf[cur] before tile t+1 overwrites it
        __syncthreads();
    }

    // ---- epilogue: C/D layout col=lane&15, row=(lane>>4)*4+r ----
    float bs[4];
#pragma unroll
    for (int fj = 0; fj < 4; ++fj)
        bs[fj] = bias ? bias[bn + wn * 64 + fj * 16 + l15] : 0.f;

#pragma unroll
    for (int fi = 0; fi < 4; ++fi) {
#pragma unroll
        for (int r = 0; r < 4; ++r) {
            int row = bm + wm * 64 + fi * 16 + l4 * 4 + r;
            if (row >= M) continue;
#pragma unroll
            for (int fj = 0; fj < 4; ++fj) {
                int col = bn + wn * 64 + fj * 16 + l15;
                float v = acc[fi][fj][r] + bs[fj];
                if (act) v = v > 0.f ? v : 0.01f * v;
                if (C) {
                    C[(size_t)row * ldc + col] = v;
                    if (C2) C2[(size_t)row * ldc + col] = v;
                }
                if (Ch) {
                    unsigned short h = f2bf(v);
                    Ch[(size_t)row * ldcp + col] = h;
                    Cl[(size_t)row * ldcp + col] =
                        f2bf(v - __uint_as_float((unsigned int)h << 16));
                }
            }
        }
    }
}

// ================= fp32-A convert-in-kernel MFMA GEMM (for Wl1: A=h_out fp32) ======
__global__ __launch_bounds__(256) void gemm_mfma(
    const float* __restrict__ A, int lda,
    const unsigned short* __restrict__ BTh, const unsigned short* __restrict__ BTl,
    float* __restrict__ C, int ldc, float* __restrict__ C2,
    const float* __restrict__ bias, int M, int N, int K, int act)
{
    __shared__ unsigned short AsH[2][128 * 64];
    __shared__ unsigned short AsL[2][128 * 64];
    const int bm = blockIdx.y * 128;
    const int bn = blockIdx.x * 128;
    const int tid = threadIdx.x;
    const int lane = tid & 63;
    const int wid = tid >> 6;
    const int wm = wid >> 1, wn = wid & 1;
    const int l15 = lane & 15, l4 = lane >> 4;

    int smidx[8], sj4[8];
    const float* sptr[8];
#pragma unroll
    for (int u = 0; u < 8; ++u) {
        int fid = tid + u * 256;
        int m = fid >> 4;
        int j4 = fid & 15;
        smidx[u] = m;
        sj4[u] = j4;
        int gr = bm + m;
        sptr[u] = (gr < M) ? (A + (size_t)gr * lda + j4 * 4) : nullptr;
    }

    const unsigned short* bhp[4];
    const unsigned short* blp[4];
#pragma unroll
    for (int fj = 0; fj < 4; ++fj) {
        size_t coff = (size_t)(bn + wn * 64 + fj * 16 + l15) * (size_t)K;
        bhp[fj] = BTh + coff;
        blp[fj] = BTl + coff;
    }

    f32x4 acc[4][4] = {};
    float4 pref[8];
    const int nk = K >> 6;

#pragma unroll
    for (int u = 0; u < 8; ++u)
        pref[u] = sptr[u] ? *(const float4*)(sptr[u]) : make_float4(0.f, 0.f, 0.f, 0.f);

    for (int t = 0; t < nk; ++t) {
        const int cur = t & 1;
#pragma unroll
        for (int u = 0; u < 8; ++u) {
            float e[4] = {pref[u].x, pref[u].y, pref[u].z, pref[u].w};
            us4v h, l;
#pragma unroll
            for (int q = 0; q < 4; ++q) {
                unsigned short hh = f2bf(e[q]);
                h[q] = hh;
                l[q] = f2bf(e[q] - __uint_as_float((unsigned int)hh << 16));
            }
            int m = smidx[u], j4 = sj4[u];
            int phys = m * 64 + ((((j4 >> 1)) ^ (m & 7)) << 3) + (j4 & 1) * 4;
            *(us4v*)&AsH[cur][phys] = h;
            *(us4v*)&AsL[cur][phys] = l;
        }
        __syncthreads();

        if (t + 1 < nk) {
            const int koff = (t + 1) * 64;
#pragma unroll
            for (int u = 0; u < 8; ++u)
                pref[u] = sptr[u] ? *(const float4*)(sptr[u] + koff)
                                  : make_float4(0.f, 0.f, 0.f, 0.f);
        }

        const int k0 = t * 64;
#pragma unroll
        for (int ks = 0; ks < 2; ++ks) {
            us8v ah[4], al[4], bh[4], bl[4];
            const int kb = ks * 4 + l4;
#pragma unroll
            for (int fi = 0; fi < 4; ++fi) {
                int row = wm * 64 + fi * 16 + l15;
                int phys = row * 64 + ((kb ^ (row & 7)) << 3);
                ah[fi] = *(const us8v*)&AsH[cur][phys];
                al[fi] = *(const us8v*)&AsL[cur][phys];
            }
            const size_t kg = (size_t)(k0 + ks * 32 + l4 * 8);
#pragma unroll
            for (int fj = 0; fj < 4; ++fj) {
                bh[fj] = *(const us8v*)(bhp[fj] + kg);
                bl[fj] = *(const us8v*)(blp[fj] + kg);
            }
#pragma unroll
            for (int fj = 0; fj < 4; ++fj)
#pragma unroll
                for (int fi = 0; fi < 4; ++fi)
                    acc[fi][fj] = mfma_bf16(ah[fi], bh[fj], acc[fi][fj]);
#pragma unroll
            for (int fj = 0; fj < 4; ++fj)
#pragma unroll
                for (int fi = 0; fi < 4; ++fi)
                    acc[fi][fj] = mfma_bf16(al[fi], bh[fj], acc[fi][fj]);
#pragma unroll
            for (int fj = 0; fj < 4; ++fj)
#pragma unroll
                for (int fi = 0; fi < 4; ++fi)
                    acc[fi][fj] = mfma_bf16(ah[fi], bl[fj], acc[fi][fj]);
        }
    }

    float bs[4];
#pragma unroll
    for (int fj = 0; fj < 4; ++fj)
        bs[fj] = bias ? bias[bn + wn * 64 + fj * 16 + l15] : 0.f;

#pragma unroll
    for (int fi = 0; fi < 4; ++fi) {
#pragma unroll
        for (int r = 0; r < 4; ++r) {
            int row = bm + wm * 64 + fi * 16 + l4 * 4 + r;
            if (row >= M) continue;
#pragma unroll
            for (int fj = 0; fj < 4; ++fj) {
                int col = bn + wn * 64 + fj * 16 + l15;
                float v = acc[fi][fj][r] + bs[fj];
                if (act) v = v > 0.f ? v : 0.01f * v;
                C[(size_t)row * ldc + col] = v;
                if (C2) C2[(size_t)row * ldc + col] = v;
            }
        }
    }
}

// ================= fp32 fallback GEMM (K=13 slices), plane or fp32 output ==========
#define BM 128
#define BN 128
#define BK 16

__global__ __launch_bounds__(256) void gemm_kernel(
    const float* __restrict__ A, int lda,
    const float* __restrict__ B, int ldb,
    float* __restrict__ C, int ldc,
    float* __restrict__ C2,
    unsigned short* __restrict__ Ch, unsigned short* __restrict__ Cl, int ldcp,
    const float* __restrict__ bias,
    int M, int N, int K, int act)
{
    __shared__ float As[BK][BM];
    __shared__ float Bs[BK][BN];
    const int bm = blockIdx.y * BM;
    const int bn = blockIdx.x * BN;
    const int tid = threadIdx.x;
    const int tx = tid & 15;
    const int ty = tid >> 4;

    const bool avec = ((((uintptr_t)A) & 15) == 0) && ((lda & 3) == 0);

    float acc[8][8] = {};

    for (int k0 = 0; k0 < K; k0 += BK) {
        if (avec) {
#pragma unroll
            for (int it = 0; it < 2; ++it) {
                int aid = tid + it * 256;
                int m = aid >> 2;
                int kq = aid & 3;
                int gr = bm + m;
                int gk = k0 + kq * 4;
                float4 v = {0.f, 0.f, 0.f, 0.f};
                if (gr < M) {
                    if (gk + 3 < K) {
                        v = *(const float4*)(A + (size_t)gr * lda + gk);
                    } else {
                        float t0 = (gk + 0 < K) ? A[(size_t)gr * lda + gk + 0] : 0.f;
                        float t1 = (gk + 1 < K) ? A[(size_t)gr * lda + gk + 1] : 0.f;
                        float t2 = (gk + 2 < K) ? A[(size_t)gr * lda + gk + 2] : 0.f;
                        float t3 = (gk + 3 < K) ? A[(size_t)gr * lda + gk + 3] : 0.f;
                        v = make_float4(t0, t1, t2, t3);
                    }
                }
                int k = kq * 4;
                As[k + 0][m ^ (((k + 0) & 7) << 2)] = v.x;
                As[k + 1][m ^ (((k + 1) & 7) << 2)] = v.y;
                As[k + 2][m ^ (((k + 2) & 7) << 2)] = v.z;
                As[k + 3][m ^ (((k + 3) & 7) << 2)] = v.w;
            }
        } else {
            for (int l = tid; l < BM * BK; l += 256) {
                int m = l >> 4;
                int k = l & 15;
                int gr = bm + m, gc = k0 + k;
                float v = (gr < M && gc < K) ? A[(size_t)gr * lda + gc] : 0.f;
                As[k][m ^ ((k & 7) << 2)] = v;
            }
        }
#pragma unroll
        for (int it = 0; it < 2; ++it) {
            int fid = tid + it * 256;
            int k = fid >> 5;
            int n4 = fid & 31;
            int gk = k0 + k;
            int gn = bn + n4 * 4;
            float4 v = {0.f, 0.f, 0.f, 0.f};
            if (gk < K) {
                if (gn + 3 < N) {
                    v = *(const float4*)(B + (size_t)gk * ldb + gn);
                } else {
                    float t0 = (gn + 0 < N) ? B[(size_t)gk * ldb + gn + 0] : 0.f;
                    float t1 = (gn + 1 < N) ? B[(size_t)gk * ldb + gn + 1] : 0.f;
                    float t2 = (gn + 2 < N) ? B[(size_t)gk * ldb + gn + 2] : 0.f;
                    float t3 = (gn + 3 < N) ? B[(size_t)gk * ldb + gn + 3] : 0.f;
                    v = make_float4(t0, t1, t2, t3);
                }
            }
            *(float4*)&Bs[k][n4 * 4] = v;
        }
        __syncthreads();

#pragma unroll
        for (int k = 0; k < BK; ++k) {
            const int sw = (k & 7) << 2;
            float4 a0 = *(const float4*)&As[k][(ty * 4) ^ sw];
            float4 a1 = *(const float4*)&As[k][(ty * 4 + 64) ^ sw];
            float4 b0 = *(const float4*)&Bs[k][tx * 4];
            float4 b1 = *(const float4*)&Bs[k][tx * 4 + 64];
            float av[8] = {a0.x, a0.y, a0.z, a0.w, a1.x, a1.y, a1.z, a1.w};
            float bv[8] = {b0.x, b0.y, b0.z, b0.w, b1.x, b1.y, b1.z, b1.w};
#pragma unroll
            for (int i = 0; i < 8; ++i)
#pragma unroll
                for (int j = 0; j < 8; ++j)
                    acc[i][j] += av[i] * bv[j];
        }
        __syncthreads();
    }

#pragma unroll
    for (int i = 0; i < 8; ++i) {
        int r = bm + ((i >> 2) * 64) + ty * 4 + (i & 3);
        if (r >= M) continue;
#pragma unroll
        for (int jh = 0; jh < 2; ++jh) {
            int c0 = bn + jh * 64 + tx * 4;
#pragma unroll
            for (int e = 0; e < 4; ++e) {
                int c = c0 + e;
                if (c >= N) continue;
                float v = acc[i][jh * 4 + e];
                if (bias) v += bias[c];
                if (act) v = v > 0.f ? v : 0.01f * v;
                if (Ch) {
                    unsigned short h = f2bf(v);
                    Ch[(size_t)r * ldcp + c] = h;
                    Cl[(size_t)r * ldcp + c] =
                        f2bf(v - __uint_as_float((unsigned int)h << 16));
                } else {
                    C[(size_t)r * ldc + c] = v;
                    if (C2) C2[(size_t)r * ldc + c] = v;
                }
            }
        }
    }
}

// ---------------- CSR build ----------------
__global__ void count_deg(const int* __restrict__ dst, int* __restrict__ deg, int nE)
{
    int e = blockIdx.x * 256 + threadIdx.x;
    if (e < nE) atomicAdd(&deg[dst[e]], 1);
}

__global__ void dinv_kernel(const int* __restrict__ deg, float* __restrict__ dinv, int n)
{
    int i = blockIdx.x * 256 + threadIdx.x;
    if (i < n) dinv[i] = rsqrtf((float)deg[i] + 1.0f);
}

__global__ __launch_bounds__(256) void scan1(const int* __restrict__ deg,
                                             int* __restrict__ excl,
                                             int* __restrict__ blocksum, int n)
{
    __shared__ int tsum[256];
    int base = blockIdx.x * 1024;
    int t = threadIdx.x;
    int v[4], s = 0;
#pragma unroll
    for (int j = 0; j < 4; ++j) {
        int idx = base + t * 4 + j;
        v[j] = (idx < n) ? deg[idx] : 0;
        s += v[j];
    }
    tsum[t] = s;
    __syncthreads();
    for (int off = 1; off < 256; off <<= 1) {
        int x = (t >= off) ? tsum[t - off] : 0;
        __syncthreads();
        tsum[t] += x;
        __syncthreads();
    }
    int toff = tsum[t] - s;
    int run = 0;
#pragma unroll
    for (int j = 0; j < 4; ++j) {
        int idx = base + t * 4 + j;
        if (idx < n) excl[idx] = toff + run;
        run += v[j];
    }
    if (t == 255) blocksum[blockIdx.x] = tsum[255];
}

__global__ void scan2(int* __restrict__ blocksum, int nb)
{
    if (threadIdx.x == 0 && blockIdx.x == 0) {
        int run = 0;
        for (int i = 0; i < nb; ++i) {
            int v = blocksum[i];
            blocksum[i] = run;
            run += v;
        }
    }
}

__global__ void scan3(int* __restrict__ rowptr, int* __restrict__ cursor,
                      const int* __restrict__ excl, const int* __restrict__ blocksum, int n)
{
    int idx = blockIdx.x * 256 + threadIdx.x;
    if (idx < n) {
        int v = excl[idx] + blocksum[idx >> 10];
        rowptr[idx] = v;
        cursor[idx] = v;
    }
    if (idx == 0) rowptr[n] = NEDGES;
}

__global__ void fill_csr(const int* __restrict__ src, const int* __restrict__ dst,
                         const float* __restrict__ dinv, int* __restrict__ cursor,
                         int* __restrict__ src_sorted, float* __restrict__ w_sorted, int nE)
{
    int e = blockIdx.x * 256 + threadIdx.x;
    if (e >= nE) return;
    int s = src[e], d = dst[e];
    int pos = atomicAdd(&cursor[d], 1);
    src_sorted[pos] = s;
    w_sorted[pos] = dinv[s] * dinv[d];
}

// ---------------- fused GCN aggregation -> split-plane output ----------------
__global__ __launch_bounds__(256) void gather_conv(
    const float* __restrict__ t, const int* __restrict__ rowptr,
    const int* __restrict__ src_sorted, const float* __restrict__ w_sorted,
    const float* __restrict__ dinv, const float* __restrict__ bias,
    unsigned short* __restrict__ oh, unsigned short* __restrict__ ol, int ldcp)
{
    int node = blockIdx.x * 4 + (threadIdx.x >> 6);
    if (node >= NNODES) return;
    int lane = threadIdx.x & 63;
    int p0 = rowptr[node], p1 = rowptr[node + 1];
    const float4* tv = (const float4*)t;
    float4 acc = {0.f, 0.f, 0.f, 0.f};
    for (int p = p0; p < p1; ++p) {
        int s = src_sorted[p];
        float w = w_sorted[p];
        float4 v = tv[(size_t)s * 64 + lane];
        acc.x += v.x * w; acc.y += v.y * w; acc.z += v.z * w; acc.w += v.w * w;
    }
    float di = dinv[node];
    float w2 = di * di;
    float4 self = tv[(size_t)node * 64 + lane];
    float4 b = ((const float4*)bias)[lane];
    float e[4];
    e[0] = acc.x + self.x * w2 + b.x;
    e[1] = acc.y + self.y * w2 + b.y;
    e[2] = acc.z + self.z * w2 + b.z;
    e[3] = acc.w + self.w * w2 + b.w;
    us4v h4, l4v;
#pragma unroll
    for (int q = 0; q < 4; ++q) {
        float v = e[q] > 0.f ? e[q] : 0.01f * e[q];
        unsigned short h = f2bf(v);
        h4[q] = h;
        l4v[q] = f2bf(v - __uint_as_float((unsigned int)h << 16));
    }
    *(us4v*)(oh + (size_t)node * ldcp + lane * 4) = h4;
    *(us4v*)(ol + (size_t)node * ldcp + lane * 4) = l4v;
}

// ---------------- final: s_ci = sigmoid(s @ Wl2 + bl2), replicate x3 ----------------
__global__ __launch_bounds__(256) void rowdot_sigmoid(
    const float* __restrict__ s, const float* __restrict__ w, const float* __restrict__ b,
    float* __restrict__ out, int n)
{
    int row = blockIdx.x * 4 + (threadIdx.x >> 6);
    int lane = threadIdx.x & 63;
    if (row >= n) return;
    const float4* sr = (const float4*)(s + (size_t)row * 256);
    const float4* wr = (const float4*)w;
    float4 a = sr[lane], c = wr[lane];
    float p = a.x * c.x + a.y * c.y + a.z * c.z + a.w * c.w;
#pragma unroll
    for (int off = 32; off > 0; off >>= 1) p += __shfl_down(p, off);
    if (lane == 0) {
        float v = 1.0f / (1.0f + expf(-(p + b[0])));
        out[row] = v;
        out[n + row] = v;
        out[2 * n + row] = v;
    }
}

extern "C" void kernel_launch(void* const* d_in, const int* in_sizes, int n_in,
                              void* d_out, int out_size, void* d_ws, size_t ws_size,
                              hipStream_t stream)
{
    const float* discrete_x = (const float*)d_in[0];
    const float* continous_x = (const float*)d_in[1];
    const float* Wd  = (const float*)d_in[2];  const float* bd  = (const float*)d_in[3];
    const float* Wc1 = (const float*)d_in[4];  const float* bc1 = (const float*)d_in[5];
    const float* Wc2 = (const float*)d_in[6];  const float* bc2 = (const float*)d_in[7];
    const float* Wg0 = (const float*)d_in[8];  const float* bg0 = (const float*)d_in[9];
    const float* Wg1 = (const float*)d_in[10]; const float* bg1 = (const float*)d_in[11];
    const float* Wg2 = (const float*)d_in[12]; const float* bg2 = (const float*)d_in[13];
    const float* Wf  = (const float*)d_in[14]; const float* bf  = (const float*)d_in[15];
    const float* Wl1 = (const float*)d_in[16]; const float* bl1 = (const float*)d_in[17];
    const float* Wl2 = (const float*)d_in[18]; const float* bl2 = (const float*)d_in[19];
    const int* edge_index = (const int*)d_in[20];
    const int* src = edge_index;
    const int* dst = edge_index + NEDGES;

    float* out = (float*)d_out;
    float* ws = (float*)d_ws;

    // workspace layout — IDENTICAL footprint to the last passing run
    float* dinv       = ws;
    int*   deg        = (int*)(ws + 50048);
    int*   rowptr     = (int*)(ws + 2 * 50048);
    int*   cursor     = (int*)(ws + 3 * 50048 + 64);
    int*   excl       = (int*)(ws + 4 * 50048 + 64);
    int*   blocksum   = (int*)(ws + 5 * 50048 + 64);
    int*   src_sorted = (int*)(ws + 5 * 50048 + 128);
    float* w_sorted   = ws + 5 * 50048 + 128 + NEDGES;
    float* xcat       = w_sorted + NEDGES;                     // NNODES*1024 floats
    float* xg         = xcat + (size_t)NNODES * 1024;          // NNODES*256 floats
    float* tbuf       = xg   + (size_t)NNODES * EMB;           // NNODES*256 floats
    float* sbuf       = tbuf + (size_t)NNODES * EMB;           // NNODES*256 floats (end)

    float* h_out  = out + 3 * (size_t)NNODES;                  // NNODES*512 (in d_out)
    float* h_out2 = h_out + (size_t)NNODES * HID;              // NNODES*512 (in d_out)

    // activation planes REPLACE the fp32 buffers byte-for-byte (same footprint):
    unsigned short* xcat_h = (unsigned short*)xcat;            // [N][1024] bf16
    unsigned short* xcat_l = xcat_h + (size_t)NNODES * 1024;   // [N][1024] bf16
    unsigned short* xg_h   = (unsigned short*)xg;              // [N][256]
    unsigned short* xg_l   = xg_h + (size_t)NNODES * 256;      // [N][256]

    // weight planes + discrete planes in dead regions (no workspace extension):
    unsigned short* wl1_h = (unsigned short*)out;              // dead until rowdot
    unsigned short* wl1_l = wl1_h + 512 * 256;
    unsigned short* wd_h  = (unsigned short*)h_out2;           // dead until Wf gemm
    unsigned short* wd_l  = wd_h  + 64 * 256;
    unsigned short* wg0_h = wd_l  + 64 * 256;
    unsigned short* wg0_l = wg0_h + 64 * 256;
    unsigned short* wg1_h = wg0_l + 64 * 256;
    unsigned short* wg1_l = wg1_h + 256 * 256;
    unsigned short* wg2_h = wg1_l + 256 * 256;
    unsigned short* wg2_l = wg2_h + 256 * 256;
    unsigned short* wf_h  = (unsigned short*)sbuf;             // dead until Wl1 gemm
    unsigned short* wf_l  = wf_h + 1024 * 512;
    unsigned short* dx_h  = wf_l + 1024 * 512;                 // discrete planes [N][64]
    unsigned short* dx_l  = dx_h + (size_t)NNODES * 64;

    dim3 blk(256);
    auto gemmF = [&](const float* A, int lda, const float* B, int ldb,
                     unsigned short* ch, unsigned short* cl, int ldcp,
                     const float* bias, int M, int N, int K, int act) {
        dim3 grid((N + BN - 1) / BN, (M + BM - 1) / BM);
        hipLaunchKernelGGL(gemm_kernel, grid, blk, 0, stream,
                           A, lda, B, ldb, (float*)nullptr, 0, (float*)nullptr,
                           ch, cl, ldcp, bias, M, N, K, act);
    };
    auto gemmP = [&](const unsigned short* ah, const unsigned short* al, int lda,
                     const unsigned short* th, const unsigned short* tl,
                     float* Cf, int ldc, float* C2,
                     unsigned short* ch, unsigned short* cl, int ldcp,
                     const float* bias, int M, int N, int K, int act) {
        dim3 grid(N / 128, (M + 127) / 128);
        hipLaunchKernelGGL(gemm_mfma_p, grid, blk, 0, stream,
                           ah, al, lda, th, tl, Cf, ldc, C2, ch, cl, ldcp,
                           bias, M, N, K, act);
    };
    auto wsp = [&](const float* W, int K, int N, unsigned short* th, unsigned short* tl) {
        hipLaunchKernelGGL(wsplit, dim3((K * N + 255) / 256), blk, 0, stream, W, K, N, th, tl);
    };

    // ---- weight + discrete-x split prologue (tiny) ----
    wsp(Wd,  64,   256, wd_h,  wd_l);
    wsp(Wg0, 64,   256, wg0_h, wg0_l);
    wsp(Wg1, 256,  256, wg1_h, wg1_l);
    wsp(Wg2, 256,  256, wg2_h, wg2_l);
    wsp(Wf,  1024, 512, wf_h,  wf_l);
    wsp(Wl1, 512,  256, wl1_h, wl1_l);
    hipLaunchKernelGGL(xsplit, dim3((NNODES * 64 + 255) / 256), blk, 0, stream,
                       discrete_x, NNODES * 64, dx_h, dx_l);

    // ---- CSR build (once) + dinv ----
    hipMemsetAsync(deg, 0, NNODES * sizeof(int), stream);
    hipLaunchKernelGGL(count_deg, dim3((NEDGES + 255) / 256), blk, 0, stream, dst, deg, NEDGES);
    hipLaunchKernelGGL(dinv_kernel, dim3((NNODES + 255) / 256), blk, 0, stream, deg, dinv, NNODES);
    int nb = (NNODES + 1023) / 1024;
    hipLaunchKernelGGL(scan1, dim3(nb), blk, 0, stream, deg, excl, blocksum, NNODES);
    hipLaunchKernelGGL(scan2, dim3(1), blk, 0, stream, blocksum, nb);
    hipLaunchKernelGGL(scan3, dim3((NNODES + 255) / 256), blk, 0, stream,
                       rowptr, cursor, excl, blocksum, NNODES);
    hipLaunchKernelGGL(fill_csr, dim3((NEDGES + 255) / 256), blk, 0, stream,
                       src, dst, dinv, cursor, src_sorted, w_sorted, NEDGES);

    // ---- embeddings into xcat planes [N,1024] = [x_d | x_c1 | x_c2 | x_g2] ----
    gemmP(dx_h, dx_l, 64, wd_h, wd_l, nullptr, 0, nullptr,
          xcat_h, xcat_l, 1024, bd, NNODES, 256, 64, 1);
    gemmF(continous_x,      39, Wc1, EMB, xcat_h + 256, xcat_l + 256, 1024,
          bc1, NNODES, EMB, 13, 1);
    gemmF(continous_x + 13, 39, Wc2, EMB, xcat_h + 512, xcat_l + 512, 1024,
          bc2, NNODES, EMB, 13, 1);
    gemmP(dx_h, dx_l, 64, wg0_h, wg0_l, nullptr, 0, nullptr,
          xg_h, xg_l, 256, bg0, NNODES, 256, 64, 1);

    // ---- GCN conv 1: tbuf = xg@Wg1 (fp32); xg planes = lrelu(gather+...) ----
    gemmP(xg_h, xg_l, 256, wg1_h, wg1_l, tbuf, 256, nullptr,
          nullptr, nullptr, 0, nullptr, NNODES, 256, 256, 0);
    hipLaunchKernelGGL(gather_conv, dim3((NNODES + 3) / 4), blk, 0, stream,
                       tbuf, rowptr, src_sorted, w_sorted, dinv, bg1, xg_h, xg_l, 256);

    // ---- GCN conv 2 -> xcat plane columns 768.. ----
    gemmP(xg_h, xg_l, 256, wg2_h, wg2_l, tbuf, 256, nullptr,
          nullptr, nullptr, 0, nullptr, NNODES, 256, 256, 0);
    hipLaunchKernelGGL(gather_conv, dim3((NNODES + 3) / 4), blk, 0, stream,
                       tbuf, rowptr, src_sorted, w_sorted, dinv, bg2,
                       xcat_h + 768, xcat_l + 768, 1024);

    // ---- h_ci = lrelu(xcat @ Wf + bf) -> both d_out slots (clobbers wd..wg2, dead) ----
    gemmP(xcat_h, xcat_l, 1024, wf_h, wf_l, h_out, HID, h_out2,
          nullptr, nullptr, 0, bf, NNODES, 512, 1024, 1);

    // ---- s = lrelu(h @ Wl1 + bl1) -> sbuf (clobbers wf/dx planes, dead) ----
    {
        dim3 grid(256 / 128, (NNODES + 127) / 128);
        hipLaunchKernelGGL(gemm_mfma, grid, blk, 0, stream,
                           h_out, HID, wl1_h, wl1_l, sbuf, 256, (float*)nullptr,
                           bl1, NNODES, 256, 512, 1);
    }

    // ---- s_ci = sigmoid(s @ Wl2 + bl2) -> out[0:3N] (clobbers wl1 planes, dead) ----
    hipLaunchKernelGGL(rowdot_sigmoid, dim3((NNODES + 3) / 4), blk, 0, stream,
                       sbuf, Wl2, bl2, out, NNODES);
}

// Round 7
// 1288.448 us; speedup vs baseline: 1.0216x; 1.0102x over previous
//
#include <hip/hip_runtime.h>
#include <math.h>

#define NNODES 50000
#define NEDGES 800000
#define EMB 256
#define HID 512

// ================= split-bf16 MFMA GEMM, plane-A version =================
// A given as pre-split hi/lo bf16 planes [M][lda] (lda=K). B pre-transposed+split
// [N][K]. 128x128 tile, BK=64, 4 waves, 64x64/wave, mfma_f32_16x16x32_bf16,
// 3 products. A staged via global_load_lds(16B) with inverse-swizzled SOURCE
// addresses (linear LDS dest). B loads issued BEFORE the A-prefetch DMA so the
// counted vmcnt wait leaves the prefetch in flight. One barrier per K-tile.
// v7: bijective XCD-aware block swizzle (m204) so sibling column-blocks of an
// A-panel share one XCD's L2; optional bf16-plane C output (for h -> Wl1).

typedef __bf16 bf16x8 __attribute__((ext_vector_type(8)));
typedef float f32x4 __attribute__((ext_vector_type(4)));
typedef unsigned short us4v __attribute__((ext_vector_type(4)));
typedef unsigned short us8v __attribute__((ext_vector_type(8)));

__device__ __forceinline__ unsigned short f2bf(float x) {
    unsigned int u = __float_as_uint(x);
    u += 0x7FFF + ((u >> 16) & 1);          // RTNE
    return (unsigned short)(u >> 16);
}

__device__ __forceinline__ f32x4 mfma_bf16(us8v a, us8v b, f32x4 c) {
    return __builtin_amdgcn_mfma_f32_16x16x32_bf16(
        __builtin_bit_cast(bf16x8, a), __builtin_bit_cast(bf16x8, b), c, 0, 0, 0);
}

__device__ __forceinline__ void gl16(const unsigned short* g, unsigned short* l) {
    __builtin_amdgcn_global_load_lds(
        (const __attribute__((address_space(1))) unsigned int*)g,
        (__attribute__((address_space(3))) unsigned int*)l, 16, 0, 0);
}

// weight prep: W [K,N] fp32 -> WTh/WTl [N,K] bf16 (hi/lo split)
__global__ void wsplit(const float* __restrict__ W, int K, int N,
                       unsigned short* __restrict__ th, unsigned short* __restrict__ tl)
{
    int idx = blockIdx.x * 256 + threadIdx.x;
    if (idx >= K * N) return;
    int n = idx / K, k = idx - n * K;
    float x = W[(size_t)k * N + n];
    unsigned short h = f2bf(x);
    float hf = __uint_as_float((unsigned int)h << 16);
    th[idx] = h;
    tl[idx] = f2bf(x - hf);
}

// activation prep: X [n] fp32 -> hi/lo planes (row-major copy)
__global__ void xsplit(const float* __restrict__ X, int n,
                       unsigned short* __restrict__ xh, unsigned short* __restrict__ xl)
{
    int i = blockIdx.x * 256 + threadIdx.x;
    if (i >= n) return;
    float x = X[i];
    unsigned short h = f2bf(x);
    xh[i] = h;
    xl[i] = f2bf(x - __uint_as_float((unsigned int)h << 16));
}

__global__ __launch_bounds__(256) void gemm_mfma_p(
    const unsigned short* __restrict__ Ah, const unsigned short* __restrict__ Al, int lda,
    const unsigned short* __restrict__ BTh, const unsigned short* __restrict__ BTl,
    float* __restrict__ C, int ldc, float* __restrict__ C2,
    unsigned short* __restrict__ Ch, unsigned short* __restrict__ Cl, int ldcp,
    const float* __restrict__ bias, int M, int N, int K, int act)
{
    // LDS: element (m,kk) stored at m*64 + (((kk>>3) ^ (m&7))<<3) + (kk&7)
    __shared__ unsigned short AsH[2][128 * 64];
    __shared__ unsigned short AsL[2][128 * 64];

    // ---- bijective XCD swizzle (m204): hw linear id -> logical block so the
    //      gridDim.x sibling blocks of one A-panel land on the SAME XCD, adjacent ----
    const int gx = gridDim.x;
    const int nwg = gx * gridDim.y;
    const int hwid = blockIdx.y * gx + blockIdx.x;
    const int q8 = nwg >> 3, r8 = nwg & 7;
    const int xcd = hwid & 7, pos = hwid >> 3;
    const int logical = (xcd < r8) ? (xcd * (q8 + 1) + pos)
                                   : (r8 * (q8 + 1) + (xcd - r8) * q8 + pos);
    const int bm = (logical / gx) * 128;
    const int bn = (logical % gx) * 128;

    const int tid = threadIdx.x;
    const int lane = tid & 63;
    const int wid = tid >> 6;                // 4 waves
    const int wm = wid >> 1, wn = wid & 1;   // 2x2 wave grid, 64x64 each
    const int l15 = lane & 15, l4 = lane >> 4;

    // staging: wave stages 4 groups (8 rows each) per plane via global_load_lds.
    // lane l writes LDS byte grp*1024 + l*16 -> row grp*8 + (l>>3), phys block l&7.
    // source block = (l&7) ^ (l>>3) so phys block b at row r holds global block b^(r&7).
    const int rg = lane >> 3;
    const int sb = (lane & 7) ^ rg;
    size_t soff[4];
#pragma unroll
    for (int i = 0; i < 4; ++i) {
        int g = wid * 4 + i;
        soff[i] = (size_t)(bm + g * 8 + rg) * (size_t)lda + (size_t)(sb * 8);
    }

    // B fragment base pointers (per wave/lane, fixed across K)
    const unsigned short* bhp[4];
    const unsigned short* blp[4];
#pragma unroll
    for (int fj = 0; fj < 4; ++fj) {
        size_t coff = (size_t)(bn + wn * 64 + fj * 16 + l15) * (size_t)K;
        bhp[fj] = BTh + coff;
        blp[fj] = BTl + coff;
    }

    f32x4 acc[4][4] = {};
    const int nk = K >> 6;                   // K/64 tiles

    // prologue: DMA tile 0 into buf 0
#pragma unroll
    for (int i = 0; i < 4; ++i) {
        int g = wid * 4 + i;
        gl16(Ah + soff[i], &AsH[0][g * 512]);
        gl16(Al + soff[i], &AsL[0][g * 512]);
    }
    __syncthreads();

    for (int t = 0; t < nk; ++t) {
        const int cur = t & 1;
        const int k0 = t * 64;

        // ---- B loads for BOTH ks-steps, issued first (counted vmcnt won't drain DMA) ----
        us8v bh[2][4], bl[2][4];
#pragma unroll
        for (int ks = 0; ks < 2; ++ks) {
            const size_t kg = (size_t)(k0 + ks * 32 + l4 * 8);
#pragma unroll
            for (int fj = 0; fj < 4; ++fj) {
                bh[ks][fj] = *(const us8v*)(bhp[fj] + kg);
                bl[ks][fj] = *(const us8v*)(blp[fj] + kg);
            }
        }

        // ---- A-prefetch tile t+1 -> buf cur^1 (in flight across the compute) ----
        if (t + 1 < nk) {
            const size_t ko = (size_t)(k0 + 64);
#pragma unroll
            for (int i = 0; i < 4; ++i) {
                int g = wid * 4 + i;
                gl16(Ah + soff[i] + ko, &AsH[cur ^ 1][g * 512]);
                gl16(Al + soff[i] + ko, &AsL[cur ^ 1][g * 512]);
            }
        }

        // ---- compute on buf[cur]: two K=32 MFMA steps, product-major ----
#pragma unroll
        for (int ks = 0; ks < 2; ++ks) {
            us8v ah[4], al[4];
            const int kb = ks * 4 + l4;
#pragma unroll
            for (int fi = 0; fi < 4; ++fi) {
                int row = wm * 64 + fi * 16 + l15;
                int phys = row * 64 + ((kb ^ (row & 7)) << 3);
                ah[fi] = *(const us8v*)&AsH[cur][phys];
                al[fi] = *(const us8v*)&AsL[cur][phys];
            }
#pragma unroll
            for (int fj = 0; fj < 4; ++fj)
#pragma unroll
                for (int fi = 0; fi < 4; ++fi)
                    acc[fi][fj] = mfma_bf16(ah[fi], bh[ks][fj], acc[fi][fj]);
#pragma unroll
            for (int fj = 0; fj < 4; ++fj)
#pragma unroll
                for (int fi = 0; fi < 4; ++fi)
                    acc[fi][fj] = mfma_bf16(al[fi], bh[ks][fj], acc[fi][fj]);
#pragma unroll
            for (int fj = 0; fj < 4; ++fj)
#pragma unroll
                for (int fi = 0; fi < 4; ++fi)
                    acc[fi][fj] = mfma_bf16(ah[fi], bl[ks][fj], acc[fi][fj]);
        }
        // one barrier per tile: drains the DMA (tile t+1 ready) and guarantees all
        // waves finished reading buf[cur] before tile t+1 overwrites it
        __syncthreads();
    }

    // ---- epilogue: C/D layout col=lane&15, row=(lane>>4)*4+r ----
    float bs[4];
#pragma unroll
    for (int fj = 0; fj < 4; ++fj)
        bs[fj] = bias ? bias[bn + wn * 64 + fj * 16 + l15] : 0.f;

#pragma unroll
    for (int fi = 0; fi < 4; ++fi) {
#pragma unroll
        for (int r = 0; r < 4; ++r) {
            int row = bm + wm * 64 + fi * 16 + l4 * 4 + r;
            if (row >= M) continue;
#pragma unroll
            for (int fj = 0; fj < 4; ++fj) {
                int col = bn + wn * 64 + fj * 16 + l15;
                float v = acc[fi][fj][r] + bs[fj];
                if (act) v = v > 0.f ? v : 0.01f * v;
                if (C) {
                    C[(size_t)row * ldc + col] = v;
                    if (C2) C2[(size_t)row * ldc + col] = v;
                }
                if (Ch) {
                    unsigned short h = f2bf(v);
                    Ch[(size_t)row * ldcp + col] = h;
                    Cl[(size_t)row * ldcp + col] =
                        f2bf(v - __uint_as_float((unsigned int)h << 16));
                }
            }
        }
    }
}

// ================= fp32 fallback GEMM (K=13 slices), plane or fp32 output ==========
#define BM 128
#define BN 128
#define BK 16

__global__ __launch_bounds__(256) void gemm_kernel(
    const float* __restrict__ A, int lda,
    const float* __restrict__ B, int ldb,
    float* __restrict__ C, int ldc,
    float* __restrict__ C2,
    unsigned short* __restrict__ Ch, unsigned short* __restrict__ Cl, int ldcp,
    const float* __restrict__ bias,
    int M, int N, int K, int act)
{
    __shared__ float As[BK][BM];
    __shared__ float Bs[BK][BN];
    const int bm = blockIdx.y * BM;
    const int bn = blockIdx.x * BN;
    const int tid = threadIdx.x;
    const int tx = tid & 15;
    const int ty = tid >> 4;

    const bool avec = ((((uintptr_t)A) & 15) == 0) && ((lda & 3) == 0);

    float acc[8][8] = {};

    for (int k0 = 0; k0 < K; k0 += BK) {
        if (avec) {
#pragma unroll
            for (int it = 0; it < 2; ++it) {
                int aid = tid + it * 256;
                int m = aid >> 2;
                int kq = aid & 3;
                int gr = bm + m;
                int gk = k0 + kq * 4;
                float4 v = {0.f, 0.f, 0.f, 0.f};
                if (gr < M) {
                    if (gk + 3 < K) {
                        v = *(const float4*)(A + (size_t)gr * lda + gk);
                    } else {
                        float t0 = (gk + 0 < K) ? A[(size_t)gr * lda + gk + 0] : 0.f;
                        float t1 = (gk + 1 < K) ? A[(size_t)gr * lda + gk + 1] : 0.f;
                        float t2 = (gk + 2 < K) ? A[(size_t)gr * lda + gk + 2] : 0.f;
                        float t3 = (gk + 3 < K) ? A[(size_t)gr * lda + gk + 3] : 0.f;
                        v = make_float4(t0, t1, t2, t3);
                    }
                }
                int k = kq * 4;
                As[k + 0][m ^ (((k + 0) & 7) << 2)] = v.x;
                As[k + 1][m ^ (((k + 1) & 7) << 2)] = v.y;
                As[k + 2][m ^ (((k + 2) & 7) << 2)] = v.z;
                As[k + 3][m ^ (((k + 3) & 7) << 2)] = v.w;
            }
        } else {
            for (int l = tid; l < BM * BK; l += 256) {
                int m = l >> 4;
                int k = l & 15;
                int gr = bm + m, gc = k0 + k;
                float v = (gr < M && gc < K) ? A[(size_t)gr * lda + gc] : 0.f;
                As[k][m ^ ((k & 7) << 2)] = v;
            }
        }
#pragma unroll
        for (int it = 0; it < 2; ++it) {
            int fid = tid + it * 256;
            int k = fid >> 5;
            int n4 = fid & 31;
            int gk = k0 + k;
            int gn = bn + n4 * 4;
            float4 v = {0.f, 0.f, 0.f, 0.f};
            if (gk < K) {
                if (gn + 3 < N) {
                    v = *(const float4*)(B + (size_t)gk * ldb + gn);
                } else {
                    float t0 = (gn + 0 < N) ? B[(size_t)gk * ldb + gn + 0] : 0.f;
                    float t1 = (gn + 1 < N) ? B[(size_t)gk * ldb + gn + 1] : 0.f;
                    float t2 = (gn + 2 < N) ? B[(size_t)gk * ldb + gn + 2] : 0.f;
                    float t3 = (gn + 3 < N) ? B[(size_t)gk * ldb + gn + 3] : 0.f;
                    v = make_float4(t0, t1, t2, t3);
                }
            }
            *(float4*)&Bs[k][n4 * 4] = v;
        }
        __syncthreads();

#pragma unroll
        for (int k = 0; k < BK; ++k) {
            const int sw = (k & 7) << 2;
            float4 a0 = *(const float4*)&As[k][(ty * 4) ^ sw];
            float4 a1 = *(const float4*)&As[k][(ty * 4 + 64) ^ sw];
            float4 b0 = *(const float4*)&Bs[k][tx * 4];
            float4 b1 = *(const float4*)&Bs[k][tx * 4 + 64];
            float av[8] = {a0.x, a0.y, a0.z, a0.w, a1.x, a1.y, a1.z, a1.w};
            float bv[8] = {b0.x, b0.y, b0.z, b0.w, b1.x, b1.y, b1.z, b1.w};
#pragma unroll
            for (int i = 0; i < 8; ++i)
#pragma unroll
                for (int j = 0; j < 8; ++j)
                    acc[i][j] += av[i] * bv[j];
        }
        __syncthreads();
    }

#pragma unroll
    for (int i = 0; i < 8; ++i) {
        int r = bm + ((i >> 2) * 64) + ty * 4 + (i & 3);
        if (r >= M) continue;
#pragma unroll
        for (int jh = 0; jh < 2; ++jh) {
            int c0 = bn + jh * 64 + tx * 4;
#pragma unroll
            for (int e = 0; e < 4; ++e) {
                int c = c0 + e;
                if (c >= N) continue;
                float v = acc[i][jh * 4 + e];
                if (bias) v += bias[c];
                if (act) v = v > 0.f ? v : 0.01f * v;
                if (Ch) {
                    unsigned short h = f2bf(v);
                    Ch[(size_t)r * ldcp + c] = h;
                    Cl[(size_t)r * ldcp + c] =
                        f2bf(v - __uint_as_float((unsigned int)h << 16));
                } else {
                    C[(size_t)r * ldc + c] = v;
                    if (C2) C2[(size_t)r * ldc + c] = v;
                }
            }
        }
    }
}

// ---------------- CSR build ----------------
__global__ void count_deg(const int* __restrict__ dst, int* __restrict__ deg, int nE)
{
    int e = blockIdx.x * 256 + threadIdx.x;
    if (e < nE) atomicAdd(&deg[dst[e]], 1);
}

__global__ void dinv_kernel(const int* __restrict__ deg, float* __restrict__ dinv, int n)
{
    int i = blockIdx.x * 256 + threadIdx.x;
    if (i < n) dinv[i] = rsqrtf((float)deg[i] + 1.0f);
}

__global__ __launch_bounds__(256) void scan1(const int* __restrict__ deg,
                                             int* __restrict__ excl,
                                             int* __restrict__ blocksum, int n)
{
    __shared__ int tsum[256];
    int base = blockIdx.x * 1024;
    int t = threadIdx.x;
    int v[4], s = 0;
#pragma unroll
    for (int j = 0; j < 4; ++j) {
        int idx = base + t * 4 + j;
        v[j] = (idx < n) ? deg[idx] : 0;
        s += v[j];
    }
    tsum[t] = s;
    __syncthreads();
    for (int off = 1; off < 256; off <<= 1) {
        int x = (t >= off) ? tsum[t - off] : 0;
        __syncthreads();
        tsum[t] += x;
        __syncthreads();
    }
    int toff = tsum[t] - s;
    int run = 0;
#pragma unroll
    for (int j = 0; j < 4; ++j) {
        int idx = base + t * 4 + j;
        if (idx < n) excl[idx] = toff + run;
        run += v[j];
    }
    if (t == 255) blocksum[blockIdx.x] = tsum[255];
}

__global__ void scan2(int* __restrict__ blocksum, int nb)
{
    if (threadIdx.x == 0 && blockIdx.x == 0) {
        int run = 0;
        for (int i = 0; i < nb; ++i) {
            int v = blocksum[i];
            blocksum[i] = run;
            run += v;
        }
    }
}

__global__ void scan3(int* __restrict__ rowptr, int* __restrict__ cursor,
                      const int* __restrict__ excl, const int* __restrict__ blocksum, int n)
{
    int idx = blockIdx.x * 256 + threadIdx.x;
    if (idx < n) {
        int v = excl[idx] + blocksum[idx >> 10];
        rowptr[idx] = v;
        cursor[idx] = v;
    }
    if (idx == 0) rowptr[n] = NEDGES;
}

__global__ void fill_csr(const int* __restrict__ src, const int* __restrict__ dst,
                         const float* __restrict__ dinv, int* __restrict__ cursor,
                         int* __restrict__ src_sorted, float* __restrict__ w_sorted, int nE)
{
    int e = blockIdx.x * 256 + threadIdx.x;
    if (e >= nE) return;
    int s = src[e], d = dst[e];
    int pos = atomicAdd(&cursor[d], 1);
    src_sorted[pos] = s;
    w_sorted[pos] = dinv[s] * dinv[d];
}

// ---------------- fused GCN aggregation -> split-plane output ----------------
__global__ __launch_bounds__(256) void gather_conv(
    const float* __restrict__ t, const int* __restrict__ rowptr,
    const int* __restrict__ src_sorted, const float* __restrict__ w_sorted,
    const float* __restrict__ dinv, const float* __restrict__ bias,
    unsigned short* __restrict__ oh, unsigned short* __restrict__ ol, int ldcp)
{
    int node = blockIdx.x * 4 + (threadIdx.x >> 6);
    if (node >= NNODES) return;
    int lane = threadIdx.x & 63;
    int p0 = rowptr[node], p1 = rowptr[node + 1];
    const float4* tv = (const float4*)t;
    float4 acc = {0.f, 0.f, 0.f, 0.f};
    for (int p = p0; p < p1; ++p) {
        int s = src_sorted[p];
        float w = w_sorted[p];
        float4 v = tv[(size_t)s * 64 + lane];
        acc.x += v.x * w; acc.y += v.y * w; acc.z += v.z * w; acc.w += v.w * w;
    }
    float di = dinv[node];
    float w2 = di * di;
    float4 self = tv[(size_t)node * 64 + lane];
    float4 b = ((const float4*)bias)[lane];
    float e[4];
    e[0] = acc.x + self.x * w2 + b.x;
    e[1] = acc.y + self.y * w2 + b.y;
    e[2] = acc.z + self.z * w2 + b.z;
    e[3] = acc.w + self.w * w2 + b.w;
    us4v h4, l4v;
#pragma unroll
    for (int q = 0; q < 4; ++q) {
        float v = e[q] > 0.f ? e[q] : 0.01f * e[q];
        unsigned short h = f2bf(v);
        h4[q] = h;
        l4v[q] = f2bf(v - __uint_as_float((unsigned int)h << 16));
    }
    *(us4v*)(oh + (size_t)node * ldcp + lane * 4) = h4;
    *(us4v*)(ol + (size_t)node * ldcp + lane * 4) = l4v;
}

// ---------------- final: s_ci = sigmoid(s @ Wl2 + bl2), replicate x3 ----------------
__global__ __launch_bounds__(256) void rowdot_sigmoid(
    const float* __restrict__ s, const float* __restrict__ w, const float* __restrict__ b,
    float* __restrict__ out, int n)
{
    int row = blockIdx.x * 4 + (threadIdx.x >> 6);
    int lane = threadIdx.x & 63;
    if (row >= n) return;
    const float4* sr = (const float4*)(s + (size_t)row * 256);
    const float4* wr = (const float4*)w;
    float4 a = sr[lane], c = wr[lane];
    float p = a.x * c.x + a.y * c.y + a.z * c.z + a.w * c.w;
#pragma unroll
    for (int off = 32; off > 0; off >>= 1) p += __shfl_down(p, off);
    if (lane == 0) {
        float v = 1.0f / (1.0f + expf(-(p + b[0])));
        out[row] = v;
        out[n + row] = v;
        out[2 * n + row] = v;
    }
}

extern "C" void kernel_launch(void* const* d_in, const int* in_sizes, int n_in,
                              void* d_out, int out_size, void* d_ws, size_t ws_size,
                              hipStream_t stream)
{
    const float* discrete_x = (const float*)d_in[0];
    const float* continous_x = (const float*)d_in[1];
    const float* Wd  = (const float*)d_in[2];  const float* bd  = (const float*)d_in[3];
    const float* Wc1 = (const float*)d_in[4];  const float* bc1 = (const float*)d_in[5];
    const float* Wc2 = (const float*)d_in[6];  const float* bc2 = (const float*)d_in[7];
    const float* Wg0 = (const float*)d_in[8];  const float* bg0 = (const float*)d_in[9];
    const float* Wg1 = (const float*)d_in[10]; const float* bg1 = (const float*)d_in[11];
    const float* Wg2 = (const float*)d_in[12]; const float* bg2 = (const float*)d_in[13];
    const float* Wf  = (const float*)d_in[14]; const float* bf  = (const float*)d_in[15];
    const float* Wl1 = (const float*)d_in[16]; const float* bl1 = (const float*)d_in[17];
    const float* Wl2 = (const float*)d_in[18]; const float* bl2 = (const float*)d_in[19];
    const int* edge_index = (const int*)d_in[20];
    const int* src = edge_index;
    const int* dst = edge_index + NEDGES;

    float* out = (float*)d_out;
    float* ws = (float*)d_ws;

    // workspace layout — IDENTICAL footprint to the last passing run
    float* dinv       = ws;
    int*   deg        = (int*)(ws + 50048);
    int*   rowptr     = (int*)(ws + 2 * 50048);
    int*   cursor     = (int*)(ws + 3 * 50048 + 64);
    int*   excl       = (int*)(ws + 4 * 50048 + 64);
    int*   blocksum   = (int*)(ws + 5 * 50048 + 64);
    int*   src_sorted = (int*)(ws + 5 * 50048 + 128);
    float* w_sorted   = ws + 5 * 50048 + 128 + NEDGES;
    float* xcat       = w_sorted + NEDGES;                     // NNODES*1024 floats
    float* xg         = xcat + (size_t)NNODES * 1024;          // NNODES*256 floats
    float* tbuf       = xg   + (size_t)NNODES * EMB;           // NNODES*256 floats
    float* sbuf       = tbuf + (size_t)NNODES * EMB;           // NNODES*256 floats (end)

    float* h_out  = out + 3 * (size_t)NNODES;                  // NNODES*512 (in d_out)
    float* h_out2 = h_out + (size_t)NNODES * HID;              // NNODES*512 (in d_out)

    // activation planes REPLACE the fp32 buffers byte-for-byte (same footprint):
    unsigned short* xcat_h = (unsigned short*)xcat;            // [N][1024] bf16
    unsigned short* xcat_l = xcat_h + (size_t)NNODES * 1024;   // [N][1024] bf16
    unsigned short* xg_h   = (unsigned short*)xg;              // [N][256]
    unsigned short* xg_l   = xg_h + (size_t)NNODES * 256;      // [N][256]

    // h planes for the Wl1 GEMM: xg region (51.2MB) and tbuf (51.2MB) are both
    // dead after gather2; each holds exactly NNODES*512 bf16.
    unsigned short* h_hi = (unsigned short*)xg;
    unsigned short* h_lo = (unsigned short*)tbuf;

    // weight planes + discrete planes in dead regions (no workspace extension):
    unsigned short* wl1_h = (unsigned short*)out;              // dead until rowdot
    unsigned short* wl1_l = wl1_h + 512 * 256;
    unsigned short* wd_h  = (unsigned short*)h_out2;           // dead until Wf gemm
    unsigned short* wd_l  = wd_h  + 64 * 256;
    unsigned short* wg0_h = wd_l  + 64 * 256;
    unsigned short* wg0_l = wg0_h + 64 * 256;
    unsigned short* wg1_h = wg0_l + 64 * 256;
    unsigned short* wg1_l = wg1_h + 256 * 256;
    unsigned short* wg2_h = wg1_l + 256 * 256;
    unsigned short* wg2_l = wg2_h + 256 * 256;
    unsigned short* wf_h  = (unsigned short*)sbuf;             // dead until Wl1 gemm
    unsigned short* wf_l  = wf_h + 1024 * 512;
    unsigned short* dx_h  = wf_l + 1024 * 512;                 // discrete planes [N][64]
    unsigned short* dx_l  = dx_h + (size_t)NNODES * 64;

    dim3 blk(256);
    auto gemmF = [&](const float* A, int lda, const float* B, int ldb,
                     unsigned short* ch, unsigned short* cl, int ldcp,
                     const float* bias, int M, int N, int K, int act) {
        dim3 grid((N + BN - 1) / BN, (M + BM - 1) / BM);
        hipLaunchKernelGGL(gemm_kernel, grid, blk, 0, stream,
                           A, lda, B, ldb, (float*)nullptr, 0, (float*)nullptr,
                           ch, cl, ldcp, bias, M, N, K, act);
    };
    auto gemmP = [&](const unsigned short* ah, const unsigned short* al, int lda,
                     const unsigned short* th, const unsigned short* tl,
                     float* Cf, int ldc, float* C2,
                     unsigned short* ch, unsigned short* cl, int ldcp,
                     const float* bias, int M, int N, int K, int act) {
        dim3 grid(N / 128, (M + 127) / 128);
        hipLaunchKernelGGL(gemm_mfma_p, grid, blk, 0, stream,
                           ah, al, lda, th, tl, Cf, ldc, C2, ch, cl, ldcp,
                           bias, M, N, K, act);
    };
    auto wsp = [&](const float* W, int K, int N, unsigned short* th, unsigned short* tl) {
        hipLaunchKernelGGL(wsplit, dim3((K * N + 255) / 256), blk, 0, stream, W, K, N, th, tl);
    };

    // ---- weight + discrete-x split prologue (tiny) ----
    wsp(Wd,  64,   256, wd_h,  wd_l);
    wsp(Wg0, 64,   256, wg0_h, wg0_l);
    wsp(Wg1, 256,  256, wg1_h, wg1_l);
    wsp(Wg2, 256,  256, wg2_h, wg2_l);
    wsp(Wf,  1024, 512, wf_h,  wf_l);
    wsp(Wl1, 512,  256, wl1_h, wl1_l);
    hipLaunchKernelGGL(xsplit, dim3((NNODES * 64 + 255) / 256), blk, 0, stream,
                       discrete_x, NNODES * 64, dx_h, dx_l);

    // ---- CSR build (once) + dinv ----
    hipMemsetAsync(deg, 0, NNODES * sizeof(int), stream);
    hipLaunchKernelGGL(count_deg, dim3((NEDGES + 255) / 256), blk, 0, stream, dst, deg, NEDGES);
    hipLaunchKernelGGL(dinv_kernel, dim3((NNODES + 255) / 256), blk, 0, stream, deg, dinv, NNODES);
    int nb = (NNODES + 1023) / 1024;
    hipLaunchKernelGGL(scan1, dim3(nb), blk, 0, stream, deg, excl, blocksum, NNODES);
    hipLaunchKernelGGL(scan2, dim3(1), blk, 0, stream, blocksum, nb);
    hipLaunchKernelGGL(scan3, dim3((NNODES + 255) / 256), blk, 0, stream,
                       rowptr, cursor, excl, blocksum, NNODES);
    hipLaunchKernelGGL(fill_csr, dim3((NEDGES + 255) / 256), blk, 0, stream,
                       src, dst, dinv, cursor, src_sorted, w_sorted, NEDGES);

    // ---- embeddings into xcat planes [N,1024] = [x_d | x_c1 | x_c2 | x_g2] ----
    gemmP(dx_h, dx_l, 64, wd_h, wd_l, nullptr, 0, nullptr,
          xcat_h, xcat_l, 1024, bd, NNODES, 256, 64, 1);
    gemmF(continous_x,      39, Wc1, EMB, xcat_h + 256, xcat_l + 256, 1024,
          bc1, NNODES, EMB, 13, 1);
    gemmF(continous_x + 13, 39, Wc2, EMB, xcat_h + 512, xcat_l + 512, 1024,
          bc2, NNODES, EMB, 13, 1);
    gemmP(dx_h, dx_l, 64, wg0_h, wg0_l, nullptr, 0, nullptr,
          xg_h, xg_l, 256, bg0, NNODES, 256, 64, 1);

    // ---- GCN conv 1: tbuf = xg@Wg1 (fp32); xg planes = lrelu(gather+...) ----
    gemmP(xg_h, xg_l, 256, wg1_h, wg1_l, tbuf, 256, nullptr,
          nullptr, nullptr, 0, nullptr, NNODES, 256, 256, 0);
    hipLaunchKernelGGL(gather_conv, dim3((NNODES + 3) / 4), blk, 0, stream,
                       tbuf, rowptr, src_sorted, w_sorted, dinv, bg1, xg_h, xg_l, 256);

    // ---- GCN conv 2 -> xcat plane columns 768.. ----
    gemmP(xg_h, xg_l, 256, wg2_h, wg2_l, tbuf, 256, nullptr,
          nullptr, nullptr, 0, nullptr, NNODES, 256, 256, 0);
    hipLaunchKernelGGL(gather_conv, dim3((NNODES + 3) / 4), blk, 0, stream,
                       tbuf, rowptr, src_sorted, w_sorted, dinv, bg2,
                       xcat_h + 768, xcat_l + 768, 1024);

    // ---- h_ci = lrelu(xcat @ Wf + bf) -> both d_out slots AND bf16 h-planes
    //      (xg/tbuf regions are dead after gather2; wd..wg2 planes dead too) ----
    gemmP(xcat_h, xcat_l, 1024, wf_h, wf_l, h_out, HID, h_out2,
          h_hi, h_lo, HID, bf, NNODES, 512, 1024, 1);

    // ---- s = lrelu(h @ Wl1 + bl1) -> sbuf (plane path; clobbers wf/dx, dead) ----
    gemmP(h_hi, h_lo, HID, wl1_h, wl1_l, sbuf, 256, nullptr,
          nullptr, nullptr, 0, bl1, NNODES, 256, 512, 1);

    // ---- s_ci = sigmoid(s @ Wl2 + bl2) -> out[0:3N] (clobbers wl1 planes, dead) ----
    hipLaunchKernelGGL(rowdot_sigmoid, dim3((NNODES + 3) / 4), blk, 0, stream,
                       sbuf, Wl2, bl2, out, NNODES);
}